// Round 14
// baseline (100.403 us; speedup 1.0000x reference)
//
#include <hip/hip_runtime.h>
#include <hip/hip_bf16.h>
#include <stdint.h>

// NT-Xent loss, B=4096, D=256, T=0.5, eps=1e-8.
// loss_r = log(sum_{c!=r} exp(2*dot(zn_r,zn_c))) - 2*dot(zin_r, zjn_r); out = mean.
// zn_s = zn * sqrt(2*log2e) stored FP8 E4M3 -> MFMA acc = 2*log2e*dot -> exp2(acc).
// Diagonal accumulated unconditionally; subtracted in k_loss via exp2(diag) with
// diag = exact quantized self-dot.
//
// R14: OCCUPANCY VIA FP8 + (256,3). Ledger: wall-time invariant to compute (R1..R12),
// both pipes idle, 2 waves/SIMD pinned by (,2)'s 256-reg budget. bf16 footprint ~190
// can't fit (,4)'s 128 (R2/R4 spills). fp8 footprint ~126 fits (,3)'s ~170 budget ->
// 3 waves/SIMD, first real TLP increase. Full matrix (symmetry never paid: R11/R12),
// grid 1024, dbuf DMA staging (T14 reg-staging regressed in R13).

#define BROWS 4096
#define DIM   256
#define N2    8192

typedef __attribute__((ext_vector_type(4))) float f32x4;

#define S_EXP  1.6986436597467051f   /* sqrt(2*log2(e)) */
#define LN2    0.6931471805599453f

__device__ inline void gload_lds16(const void* g, void* l) {
    __builtin_amdgcn_global_load_lds(
        (const __attribute__((address_space(1))) uint32_t*)g,
        (__attribute__((address_space(3))) uint32_t*)l, 16, 0, 0);
}

__device__ inline float wave_reduce(float v) {
    #pragma unroll
    for (int m = 1; m < 64; m <<= 1) v += __shfl_xor(v, m);
    return v;
}

__device__ inline float fp8_selfdot4(int p) {
    float f0 = __builtin_amdgcn_cvt_f32_fp8(p, 0);
    float f1 = __builtin_amdgcn_cvt_f32_fp8(p, 1);
    float f2 = __builtin_amdgcn_cvt_f32_fp8(p, 2);
    float f3 = __builtin_amdgcn_cvt_f32_fp8(p, 3);
    return f0*f0 + f1*f1 + f2*f2 + f3*f3;
}

// ---- K1: fused normalize (both views) + positive-pair exponent + fp8 quantize ----
__global__ __launch_bounds__(256) void k_norm_pos(const float* __restrict__ zi,
                                                  const float* __restrict__ zj,
                                                  uint8_t* __restrict__ zn,
                                                  float* __restrict__ diag,
                                                  float* __restrict__ posv,
                                                  unsigned int* __restrict__ counter) {
    if (blockIdx.x == 0 && threadIdx.x == 0) *counter = 0u;
    int i    = blockIdx.x * 4 + (threadIdx.x >> 6);
    int lane = threadIdx.x & 63;
    f32x4 a = *(const f32x4*)(zi + (size_t)i * DIM + lane * 4);
    f32x4 b = *(const f32x4*)(zj + (size_t)i * DIM + lane * 4);
    float ssa = a[0]*a[0] + a[1]*a[1] + a[2]*a[2] + a[3]*a[3];
    float ssb = b[0]*b[0] + b[1]*b[1] + b[2]*b[2] + b[3]*b[3];
    float dab = a[0]*b[0] + a[1]*b[1] + a[2]*b[2] + a[3]*b[3];
    ssa = wave_reduce(ssa);
    ssb = wave_reduce(ssb);
    dab = wave_reduce(dab);
    float na = 1.0f / fmaxf(sqrtf(ssa), 1e-8f);
    float nb = 1.0f / fmaxf(sqrtf(ssb), 1e-8f);
    if (lane == 0) posv[i] = 2.0f * dab * na * nb;   // natural-log exponent of pos pair

    float sa = na * S_EXP, sb = nb * S_EXP;
    int pa = 0, pb = 0;
    pa = __builtin_amdgcn_cvt_pk_fp8_f32(a[0] * sa, a[1] * sa, pa, 0);
    pa = __builtin_amdgcn_cvt_pk_fp8_f32(a[2] * sa, a[3] * sa, pa, 1);
    pb = __builtin_amdgcn_cvt_pk_fp8_f32(b[0] * sb, b[1] * sb, pb, 0);
    pb = __builtin_amdgcn_cvt_pk_fp8_f32(b[2] * sb, b[3] * sb, pb, 1);
    *(uint32_t*)(zn + (size_t)i * DIM + lane * 4)           = (uint32_t)pa;
    *(uint32_t*)(zn + (size_t)(i + BROWS) * DIM + lane * 4) = (uint32_t)pb;

    float da = fp8_selfdot4(pa);
    float db = fp8_selfdot4(pb);
    da = wave_reduce(da);
    db = wave_reduce(db);
    if (lane == 0) { diag[i] = da; diag[i + BROWS] = db; }
}

// ---- K2: fused sim GEMM (fp8) + exp2 + row-sum (diagonal NOT masked) ----
// 256 thr = 4 waves; block tile 256 rows x 256 cols; grid = 32*32 = 1024.
// Wave owns 64 rows: afrag[4][8] as i64 (64 VGPRs). B double-buffered in LDS
// 2 x 16 KB, staged via global_load_lds BEFORE compute.
// LDS layout: byte = buf*16384 + kc*2048 + (g>>1)*1024 + col*16 + (g&1)*8 holds
//   zn[colbase + s*64 + col][kc*32 + g*8 .. +8]
__global__ __launch_bounds__(256, 3) void k_simsum(const uint8_t* __restrict__ zn,
                                                   float* __restrict__ partial) {
    __shared__ uint8_t lds[2][64 * DIM];   // 2 x 16 KB
    // bijective XCD swizzle (grid 1024, 8 XCDs -> 128 blocks per XCD chunk)
    int sw = (blockIdx.x & 7) * 128 + (blockIdx.x >> 3);
    int rb = sw & 31;         // 32 row-blocks of 256
    int cc = sw >> 5;         // 32 col-chunks of 256
    int rowbase = rb * 256;
    int colbase = cc * 256;
    int tid = threadIdx.x, lane = tid & 63, w = tid >> 6;   // w in 0..3
    int cl = lane & 15, g = lane >> 4;

    // A fragments: lane holds zn[rowbase + w*64 + rt*16 + cl][kc*32 + g*8 .. +8]
    long long afrag[4][8];
    #pragma unroll
    for (int rt = 0; rt < 4; ++rt) {
        int row = rowbase + w * 64 + rt * 16 + cl;
        const uint8_t* ap = zn + (size_t)row * DIM + g * 8;
        #pragma unroll
        for (int kc = 0; kc < 8; ++kc)
            afrag[rt][kc] = *(const long long*)(ap + kc * 32);
    }

    float pp[4][4];
    #pragma unroll
    for (int rt = 0; rt < 4; ++rt)
        #pragma unroll
        for (int r = 0; r < 4; ++r) pp[rt][r] = 0.0f;

    // stage 64 cols x 256 K (fp8) into lds[buf]: 256 thr x 16 B x 4 issues = 16 KB
    auto stage = [&](int buf, int s) {
        const uint8_t* rowptr = zn + (size_t)(colbase + s * 64 + lane) * DIM;
        char* base = (char*)&lds[buf][0];
        #pragma unroll
        for (int j = 0; j < 4; ++j) {
            int p = w * 4 + j;              // p = kc*2 + half, p in 0..15
            gload_lds16(rowptr + (p >> 1) * 32 + (p & 1) * 16,
                        base + (p >> 1) * 2048 + (p & 1) * 1024);
        }
    };

    stage(0, 0);
    __syncthreads();   // prologue: buf0 ready

    for (int s = 0; s < 4; ++s) {
        int cur = s & 1;
        if (s < 3) stage(cur ^ 1, s + 1);   // issue next-tile loads BEFORE compute

        const char* lbase = (const char*)&lds[cur][0];
        #pragma unroll
        for (int ct = 0; ct < 4; ++ct) {
            f32x4 acc[4];
            #pragma unroll
            for (int rt = 0; rt < 4; ++rt) acc[rt] = (f32x4){0.f, 0.f, 0.f, 0.f};
            #pragma unroll
            for (int kc = 0; kc < 8; ++kc) {
                long long bfrag = *(const long long*)(lbase + kc * 2048 +
                                      (g >> 1) * 1024 + (ct * 16 + cl) * 16 +
                                      (g & 1) * 8);
                #pragma unroll
                for (int rt = 0; rt < 4; ++rt)
                    acc[rt] = __builtin_amdgcn_mfma_f32_16x16x32_fp8_fp8(
                                  afrag[rt][kc], bfrag, acc[rt], 0, 0, 0);
            }
            #pragma unroll
            for (int rt = 0; rt < 4; ++rt)
                #pragma unroll
                for (int r = 0; r < 4; ++r)
                    pp[rt][r] += __builtin_amdgcn_exp2f(acc[rt][r]);
        }
        __syncthreads();   // drains vmcnt (next buf staged) + lgkmcnt (cur reads done)
    }

    // reduce across the 16 col-lanes (cl) within each g-group
    #pragma unroll
    for (int rt = 0; rt < 4; ++rt) {
        #pragma unroll
        for (int r = 0; r < 4; ++r) {
            float v = pp[rt][r];
            v += __shfl_xor(v, 1);
            v += __shfl_xor(v, 2);
            v += __shfl_xor(v, 4);
            v += __shfl_xor(v, 8);
            if (cl == 0)
                partial[(size_t)cc * N2 + rowbase + w * 64 + rt * 16 + g * 4 + r] = v;
        }
    }
}

// ---- K3: per-row loss over 32 blocks; last block finishes the mean ----
__global__ __launch_bounds__(256) void k_loss(const float* __restrict__ partial,
                                              const float* __restrict__ diag,
                                              const float* __restrict__ posv,
                                              float* __restrict__ blocksum,
                                              unsigned int* __restrict__ counter,
                                              float* __restrict__ out) {
    int row = blockIdx.x * 256 + threadIdx.x;
    float sum = 0.0f;
    #pragma unroll
    for (int c = 0; c < 32; ++c) sum += partial[(size_t)c * N2 + row];
    sum -= __builtin_amdgcn_exp2f(diag[row]);           // remove diagonal term
    float lr = __builtin_amdgcn_logf(sum) * LN2 - posv[row & (BROWS - 1)];
    lr = wave_reduce(lr);
    __shared__ float red[4];
    if ((threadIdx.x & 63) == 0) red[threadIdx.x >> 6] = lr;
    __syncthreads();
    if (threadIdx.x == 0) {
        blocksum[blockIdx.x] = red[0] + red[1] + red[2] + red[3];
        __threadfence();                                  // publish blocksum
        unsigned int old = atomicAdd(counter, 1u);        // device-scope
        if (old == 31u) {                                 // last block finishes
            __threadfence();                              // acquire
            volatile const float* bs = blocksum;
            float t = 0.0f;
            for (int i = 0; i < 32; ++i) t += bs[i];
            out[0] = t * (1.0f / N2);
        }
    }
}

extern "C" void kernel_launch(void* const* d_in, const int* in_sizes, int n_in,
                              void* d_out, int out_size, void* d_ws, size_t ws_size,
                              hipStream_t stream) {
    const float* zi = (const float*)d_in[0];
    const float* zj = (const float*)d_in[1];
    float* out = (float*)d_out;

    char* ws = (char*)d_ws;
    uint8_t* zn           = (uint8_t*)ws;                              // 2 MB
    float* diag           = (float*)(ws + (2u << 20));                 // 32 KB
    float* posv           = (float*)(ws + (2u << 20) + (32u << 10));   // 16 KB
    float* blocksum       = (float*)(ws + (2u << 20) + (48u << 10));   // 128 B
    unsigned int* counter = (unsigned int*)(ws + (2u << 20) + (52u << 10));
    float* partial        = (float*)(ws + (2u << 20) + (64u << 10));   // 1 MB

    k_norm_pos<<<BROWS / 4, 256, 0, stream>>>(zi, zj, zn, diag, posv, counter);
    k_simsum<<<1024, 256, 0, stream>>>(zn, partial);
    k_loss<<<32, 256, 0, stream>>>(partial, diag, posv, blocksum, counter, out);
}

// Round 15
// 85.265 us; speedup vs baseline: 1.1775x; 1.1775x over previous
//
#include <hip/hip_runtime.h>
#include <hip/hip_bf16.h>
#include <stdint.h>

// NT-Xent loss, B=4096, D=256, T=0.5, eps=1e-8.
// loss_r = log(sum_{c!=r} exp(2*dot(zn_r,zn_c))) - 2*dot(zin_r, zjn_r); out = mean.
// zn_s = zn * sqrt(2*log2e) stored bf16 -> MFMA acc = 2*log2e*dot -> exp2(acc) direct.
// Diagonal accumulated unconditionally; subtracted in k_loss via exp2(diag).
//
// R15: SLIM WAVES FOR OCCUPANCY. Measured law: launch_bounds arg2 -> arch-VGPR cap
// ~= 256/arg2 (2->128, 3->84, 4->64). bf16 64-row waves need afrag=128 -> pinned at
// 2 waves/SIMD (latency-exposed, MfmaUtil 28%). This round: 32-row waves, afrag[2][8]
// = 64 VGPR, arch ~110 < 128 cap of (512,2), unified ~125/wave -> 16 waves/CU =
// 4 waves/SIMD. Block = 8 waves x 32 rows = 256 rows x 512 cols (R1's L2-clean
// footprint), grid 512 = 2 blocks/CU, dbuf stage-early (R3 order).

#define BROWS 4096
#define DIM   256
#define N2    8192

typedef __attribute__((ext_vector_type(4))) float          f32x4;
typedef __attribute__((ext_vector_type(8))) short          s16x8;
typedef __attribute__((ext_vector_type(4))) unsigned short u16x4;

#define S_EXP  1.6986436597467051f   /* sqrt(2*log2(e)) */
#define LN2    0.6931471805599453f

__device__ inline unsigned short f2bf(float f) {
    uint32_t b = __float_as_uint(f);
    b += 0x7fffu + ((b >> 16) & 1u);   // RNE
    return (unsigned short)(b >> 16);
}
__device__ inline float bf2f(unsigned short u) {
    return __uint_as_float(((uint32_t)u) << 16);
}

__device__ inline void gload_lds16(const void* g, void* l) {
    __builtin_amdgcn_global_load_lds(
        (const __attribute__((address_space(1))) uint32_t*)g,
        (__attribute__((address_space(3))) uint32_t*)l, 16, 0, 0);
}

__device__ inline float wave_reduce(float v) {
    #pragma unroll
    for (int m = 1; m < 64; m <<= 1) v += __shfl_xor(v, m);
    return v;
}

// ---- K1: fused normalize (both views) + positive-pair exponent + diag self-dot ----
__global__ __launch_bounds__(256) void k_norm_pos(const float* __restrict__ zi,
                                                  const float* __restrict__ zj,
                                                  unsigned short* __restrict__ zn,
                                                  float* __restrict__ diag,
                                                  float* __restrict__ posv,
                                                  unsigned int* __restrict__ counter) {
    if (blockIdx.x == 0 && threadIdx.x == 0) *counter = 0u;
    int i    = blockIdx.x * 4 + (threadIdx.x >> 6);
    int lane = threadIdx.x & 63;
    f32x4 a = *(const f32x4*)(zi + (size_t)i * DIM + lane * 4);
    f32x4 b = *(const f32x4*)(zj + (size_t)i * DIM + lane * 4);
    float ssa = a[0]*a[0] + a[1]*a[1] + a[2]*a[2] + a[3]*a[3];
    float ssb = b[0]*b[0] + b[1]*b[1] + b[2]*b[2] + b[3]*b[3];
    float dab = a[0]*b[0] + a[1]*b[1] + a[2]*b[2] + a[3]*b[3];
    ssa = wave_reduce(ssa);
    ssb = wave_reduce(ssb);
    dab = wave_reduce(dab);
    float na = 1.0f / fmaxf(sqrtf(ssa), 1e-8f);
    float nb = 1.0f / fmaxf(sqrtf(ssb), 1e-8f);
    if (lane == 0) posv[i] = 2.0f * dab * na * nb;   // natural-log exponent of pos pair

    float sa = na * S_EXP, sb = nb * S_EXP;
    u16x4 oa, ob;
    float da = 0.0f, db = 0.0f;
    #pragma unroll
    for (int k = 0; k < 4; ++k) {
        unsigned short ua = f2bf(a[k] * sa);
        unsigned short ub = f2bf(b[k] * sb);
        oa[k] = ua; ob[k] = ub;
        float fa = bf2f(ua), fb = bf2f(ub);
        da += fa * fa; db += fb * fb;
    }
    *(u16x4*)(zn + (size_t)i * DIM + lane * 4)           = oa;
    *(u16x4*)(zn + (size_t)(i + BROWS) * DIM + lane * 4) = ob;
    da = wave_reduce(da);
    db = wave_reduce(db);
    if (lane == 0) { diag[i] = da; diag[i + BROWS] = db; }
}

// ---- K2: fused sim GEMM + exp2 + row-sum (diagonal NOT masked) ----
// 512 thr = 8 waves; block tile 256 rows x 512 cols; grid = 32*16 = 512.
// Wave owns 32 rows (afrag[2][8] = 64 VGPR). B dbuf LDS 2x32KB, stage-early.
// LDS layout: byte = buf*32768 + kc*4096 + g*1024 + col*16
//   holds zn[colbase + s*64 + col][kc*32 + g*8 .. +8]
__global__ __launch_bounds__(512, 2) void k_simsum(const unsigned short* __restrict__ zn,
                                                   float* __restrict__ partial) {
    __shared__ unsigned short lds[2][64 * DIM];   // 2 x 32 KB
    int bid = blockIdx.x;
    int rb = bid & 31;        // 32 row-blocks of 256
    int cc = bid >> 5;        // 16 col-chunks of 512
    int rowbase = rb * 256;
    int colbase = cc * 512;
    int tid = threadIdx.x, lane = tid & 63, w = tid >> 6;   // w in 0..7
    int cl = lane & 15, g = lane >> 4;

    // A fragments: lane holds zn[rowbase + w*32 + rt*16 + cl][kc*32 + g*8 .. +8]
    s16x8 afrag[2][8];
    #pragma unroll
    for (int rt = 0; rt < 2; ++rt) {
        int row = rowbase + w * 32 + rt * 16 + cl;
        const unsigned short* ap = zn + (size_t)row * DIM + g * 8;
        #pragma unroll
        for (int kc = 0; kc < 8; ++kc)
            afrag[rt][kc] = *(const s16x8*)(ap + kc * 32);
    }

    float pp[2][4];
    #pragma unroll
    for (int rt = 0; rt < 2; ++rt)
        #pragma unroll
        for (int r = 0; r < 4; ++r) pp[rt][r] = 0.0f;

    // stage 64 cols x 256 K into lds[buf]: 512 thr x 4 x 16 B = 32 KB.
    // thread (w, lane): p = w*4+j -> kc=w>>... p=kc*4+g' with kc=p>>2=w, g'=p&3=j.
    auto stage = [&](int buf, int s) {
        const unsigned short* rowptr = zn + (size_t)(colbase + s * 64 + lane) * DIM;
        char* base = (char*)&lds[buf][0];
        #pragma unroll
        for (int j = 0; j < 4; ++j)
            gload_lds16(rowptr + w * 32 + j * 8, base + w * 4096 + j * 1024);
    };

    stage(0, 0);
    __syncthreads();   // prologue: buf0 ready

    for (int s = 0; s < 8; ++s) {
        int cur = s & 1;
        if (s < 7) stage(cur ^ 1, s + 1);   // issue next-tile loads BEFORE compute

        const char* lbase = (const char*)&lds[cur][0];
        #pragma unroll
        for (int ct = 0; ct < 4; ++ct) {
            f32x4 acc[2];
            acc[0] = (f32x4){0.f, 0.f, 0.f, 0.f};
            acc[1] = (f32x4){0.f, 0.f, 0.f, 0.f};
            #pragma unroll
            for (int kc = 0; kc < 8; ++kc) {
                s16x8 bfrag = *(const s16x8*)(lbase + kc * 4096 + g * 1024 +
                                              (ct * 16 + cl) * 16);
                acc[0] = __builtin_amdgcn_mfma_f32_16x16x32_bf16(afrag[0][kc], bfrag, acc[0], 0, 0, 0);
                acc[1] = __builtin_amdgcn_mfma_f32_16x16x32_bf16(afrag[1][kc], bfrag, acc[1], 0, 0, 0);
            }
            #pragma unroll
            for (int rt = 0; rt < 2; ++rt)
                #pragma unroll
                for (int r = 0; r < 4; ++r)
                    pp[rt][r] += __builtin_amdgcn_exp2f(acc[rt][r]);
        }
        __syncthreads();   // drains vmcnt (next buf staged) + lgkmcnt (cur reads done)
    }

    // reduce across the 16 col-lanes (cl) within each g-group
    #pragma unroll
    for (int rt = 0; rt < 2; ++rt) {
        #pragma unroll
        for (int r = 0; r < 4; ++r) {
            float v = pp[rt][r];
            v += __shfl_xor(v, 1);
            v += __shfl_xor(v, 2);
            v += __shfl_xor(v, 4);
            v += __shfl_xor(v, 8);
            if (cl == 0)
                partial[(size_t)cc * N2 + rowbase + w * 32 + rt * 16 + g * 4 + r] = v;
        }
    }
}

// ---- K3: per-row loss over 32 blocks; last block finishes the mean ----
__global__ __launch_bounds__(256) void k_loss(const float* __restrict__ partial,
                                              const float* __restrict__ diag,
                                              const float* __restrict__ posv,
                                              float* __restrict__ blocksum,
                                              unsigned int* __restrict__ counter,
                                              float* __restrict__ out) {
    int row = blockIdx.x * 256 + threadIdx.x;
    float sum = 0.0f;
    #pragma unroll
    for (int c = 0; c < 16; ++c) sum += partial[(size_t)c * N2 + row];
    sum -= __builtin_amdgcn_exp2f(diag[row]);           // remove diagonal term
    float lr = __builtin_amdgcn_logf(sum) * LN2 - posv[row & (BROWS - 1)];
    lr = wave_reduce(lr);
    __shared__ float red[4];
    if ((threadIdx.x & 63) == 0) red[threadIdx.x >> 6] = lr;
    __syncthreads();
    if (threadIdx.x == 0) {
        blocksum[blockIdx.x] = red[0] + red[1] + red[2] + red[3];
        __threadfence();                                  // publish blocksum
        unsigned int old = atomicAdd(counter, 1u);        // device-scope
        if (old == 31u) {                                 // last block finishes
            __threadfence();                              // acquire
            volatile const float* bs = blocksum;
            float t = 0.0f;
            for (int i = 0; i < 32; ++i) t += bs[i];
            out[0] = t * (1.0f / N2);
        }
    }
}

extern "C" void kernel_launch(void* const* d_in, const int* in_sizes, int n_in,
                              void* d_out, int out_size, void* d_ws, size_t ws_size,
                              hipStream_t stream) {
    const float* zi = (const float*)d_in[0];
    const float* zj = (const float*)d_in[1];
    float* out = (float*)d_out;

    char* ws = (char*)d_ws;
    unsigned short* zn    = (unsigned short*)ws;                       // 4 MB
    float* diag           = (float*)(ws + (4u << 20));                 // 32 KB
    float* posv           = (float*)(ws + (4u << 20) + (32u << 10));   // 16 KB
    float* blocksum       = (float*)(ws + (4u << 20) + (48u << 10));   // 128 B
    unsigned int* counter = (unsigned int*)(ws + (4u << 20) + (52u << 10));
    float* partial        = (float*)(ws + (4u << 20) + (64u << 10));   // 512 KB

    k_norm_pos<<<BROWS / 4, 256, 0, stream>>>(zi, zj, zn, diag, posv, counter);
    k_simsum<<<512, 512, 0, stream>>>(zn, partial);
    k_loss<<<32, 256, 0, stream>>>(partial, diag, posv, blocksum, counter, out);
}

// Round 16
// 54.476 us; speedup vs baseline: 1.8431x; 1.5652x over previous
//
#include <hip/hip_runtime.h>
#include <hip/hip_bf16.h>
#include <stdint.h>

// NT-Xent loss, B=4096, D=256, T=0.5, eps=1e-8.
// loss_r = log(sum_{c!=r} exp(2*dot(zn_r,zn_c))) - 2*dot(zin_r, zjn_r); out = mean.
// zn_s = zn * sqrt(2*log2e) stored bf16 -> MFMA acc = 2*log2e*dot -> exp2(acc) direct.
// Diagonal accumulated unconditionally; subtracted in k_loss via exp2(diag).
//
// R16: REGISTER HEADROOM FOR LDS PREFETCH. Ledger: R1-class kernels run at 778 TF
// (85% of the m97-structure ceiling) with MfmaUtil 28% — ds_read latency exposed
// because afrag[4][8]=128 VGPR fills the whole (256,2) cap, leaving no regs to
// hoist bfrag loads. This round: 4-wave 256-thr blocks (never spill), 32 rows/wave
// (afrag[2][8]=64 VGPR, ~50 free for prefetch), block 128 rows x 1024 cols
// (16 steps of 64), grid 64x8=512 (proven-clean residency), dbuf stage-early.
//
// LESSONS: 8-wave/512-thr blocks ALWAYS spill (R2/R7/R15). launch_bounds arg2:
// arch-VGPR cap ~= 256/arg2. grid>512 thrashes L2 (FETCH 64-83MB). Health checks:
// VGPR<=128, WRITE~1-2MB, FETCH~17-25MB, conflicts 0.

#define BROWS 4096
#define DIM   256
#define N2    8192

typedef __attribute__((ext_vector_type(4))) float          f32x4;
typedef __attribute__((ext_vector_type(8))) short          s16x8;
typedef __attribute__((ext_vector_type(4))) unsigned short u16x4;

#define S_EXP  1.6986436597467051f   /* sqrt(2*log2(e)) */
#define LN2    0.6931471805599453f

__device__ inline unsigned short f2bf(float f) {
    uint32_t b = __float_as_uint(f);
    b += 0x7fffu + ((b >> 16) & 1u);   // RNE
    return (unsigned short)(b >> 16);
}
__device__ inline float bf2f(unsigned short u) {
    return __uint_as_float(((uint32_t)u) << 16);
}

__device__ inline void gload_lds16(const void* g, void* l) {
    __builtin_amdgcn_global_load_lds(
        (const __attribute__((address_space(1))) uint32_t*)g,
        (__attribute__((address_space(3))) uint32_t*)l, 16, 0, 0);
}

__device__ inline float wave_reduce(float v) {
    #pragma unroll
    for (int m = 1; m < 64; m <<= 1) v += __shfl_xor(v, m);
    return v;
}

// ---- K1: fused normalize (both views) + positive-pair exponent + diag self-dot ----
__global__ __launch_bounds__(256) void k_norm_pos(const float* __restrict__ zi,
                                                  const float* __restrict__ zj,
                                                  unsigned short* __restrict__ zn,
                                                  float* __restrict__ diag,
                                                  float* __restrict__ posv,
                                                  unsigned int* __restrict__ counter) {
    if (blockIdx.x == 0 && threadIdx.x == 0) *counter = 0u;
    int i    = blockIdx.x * 4 + (threadIdx.x >> 6);
    int lane = threadIdx.x & 63;
    f32x4 a = *(const f32x4*)(zi + (size_t)i * DIM + lane * 4);
    f32x4 b = *(const f32x4*)(zj + (size_t)i * DIM + lane * 4);
    float ssa = a[0]*a[0] + a[1]*a[1] + a[2]*a[2] + a[3]*a[3];
    float ssb = b[0]*b[0] + b[1]*b[1] + b[2]*b[2] + b[3]*b[3];
    float dab = a[0]*b[0] + a[1]*b[1] + a[2]*b[2] + a[3]*b[3];
    ssa = wave_reduce(ssa);
    ssb = wave_reduce(ssb);
    dab = wave_reduce(dab);
    float na = 1.0f / fmaxf(sqrtf(ssa), 1e-8f);
    float nb = 1.0f / fmaxf(sqrtf(ssb), 1e-8f);
    if (lane == 0) posv[i] = 2.0f * dab * na * nb;   // natural-log exponent of pos pair

    float sa = na * S_EXP, sb = nb * S_EXP;
    u16x4 oa, ob;
    float da = 0.0f, db = 0.0f;
    #pragma unroll
    for (int k = 0; k < 4; ++k) {
        unsigned short ua = f2bf(a[k] * sa);
        unsigned short ub = f2bf(b[k] * sb);
        oa[k] = ua; ob[k] = ub;
        float fa = bf2f(ua), fb = bf2f(ub);
        da += fa * fa; db += fb * fb;
    }
    *(u16x4*)(zn + (size_t)i * DIM + lane * 4)           = oa;
    *(u16x4*)(zn + (size_t)(i + BROWS) * DIM + lane * 4) = ob;
    da = wave_reduce(da);
    db = wave_reduce(db);
    if (lane == 0) { diag[i] = da; diag[i + BROWS] = db; }
}

// ---- K2: fused sim GEMM + exp2 + row-sum (diagonal NOT masked) ----
// 256 thr = 4 waves; block tile 128 rows x 1024 cols; grid = 64*8 = 512.
// Wave owns 32 rows (afrag[2][8] = 64 VGPR; ~50 regs free for bfrag prefetch).
// B dbuf LDS 2x32KB, staged BEFORE compute. 16 steps of 64 cols.
// LDS layout: byte = buf*32768 + kc*4096 + g*1024 + col*16
//   holds zn[colbase + s*64 + col][kc*32 + g*8 .. +8]
__global__ __launch_bounds__(256, 2) void k_simsum(const unsigned short* __restrict__ zn,
                                                   float* __restrict__ partial) {
    __shared__ unsigned short lds[2][64 * DIM];   // 2 x 32 KB
    int bid = blockIdx.x;
    int rb = bid & 63;        // 64 row-blocks of 128
    int cc = bid >> 6;        // 8 col-chunks of 1024
    int rowbase = rb * 128;
    int colbase = cc * 1024;
    int tid = threadIdx.x, lane = tid & 63, w = tid >> 6;   // w in 0..3
    int cl = lane & 15, g = lane >> 4;

    // A fragments: lane holds zn[rowbase + w*32 + rt*16 + cl][kc*32 + g*8 .. +8]
    s16x8 afrag[2][8];
    #pragma unroll
    for (int rt = 0; rt < 2; ++rt) {
        int row = rowbase + w * 32 + rt * 16 + cl;
        const unsigned short* ap = zn + (size_t)row * DIM + g * 8;
        #pragma unroll
        for (int kc = 0; kc < 8; ++kc)
            afrag[rt][kc] = *(const s16x8*)(ap + kc * 32);
    }

    float pp[2][4];
    #pragma unroll
    for (int rt = 0; rt < 2; ++rt)
        #pragma unroll
        for (int r = 0; r < 4; ++r) pp[rt][r] = 0.0f;

    // stage 64 cols x 256 K into lds[buf]; 256 lanes x 16 B x 8 issues = 32 KB
    auto stage = [&](int buf, int s) {
        int crow = colbase + s * 64 + lane;
        const unsigned short* gsrc = zn + (size_t)crow * DIM;
        char* base = (char*)&lds[buf][0];
        #pragma unroll
        for (int i = 0; i < 8; ++i)
            gload_lds16(gsrc + i * 32 + w * 8, base + i * 4096 + w * 1024);
    };

    stage(0, 0);
    __syncthreads();   // prologue: buf0 ready

    for (int s = 0; s < 16; ++s) {
        int cur = s & 1;
        if (s < 15) stage(cur ^ 1, s + 1);   // issue next-tile loads BEFORE compute

        const char* lbase = (const char*)&lds[cur][0];
        #pragma unroll
        for (int ct = 0; ct < 4; ++ct) {
            f32x4 acc[2];
            acc[0] = (f32x4){0.f, 0.f, 0.f, 0.f};
            acc[1] = (f32x4){0.f, 0.f, 0.f, 0.f};
            #pragma unroll
            for (int kc = 0; kc < 8; ++kc) {
                s16x8 bfrag = *(const s16x8*)(lbase + kc * 4096 + g * 1024 +
                                              (ct * 16 + cl) * 16);
                acc[0] = __builtin_amdgcn_mfma_f32_16x16x32_bf16(afrag[0][kc], bfrag, acc[0], 0, 0, 0);
                acc[1] = __builtin_amdgcn_mfma_f32_16x16x32_bf16(afrag[1][kc], bfrag, acc[1], 0, 0, 0);
            }
            #pragma unroll
            for (int rt = 0; rt < 2; ++rt)
                #pragma unroll
                for (int r = 0; r < 4; ++r)
                    pp[rt][r] += __builtin_amdgcn_exp2f(acc[rt][r]);
        }
        __syncthreads();   // drains vmcnt (next buf staged) + lgkmcnt (cur reads done)
    }

    // reduce across the 16 col-lanes (cl) within each g-group
    #pragma unroll
    for (int rt = 0; rt < 2; ++rt) {
        #pragma unroll
        for (int r = 0; r < 4; ++r) {
            float v = pp[rt][r];
            v += __shfl_xor(v, 1);
            v += __shfl_xor(v, 2);
            v += __shfl_xor(v, 4);
            v += __shfl_xor(v, 8);
            if (cl == 0)
                partial[(size_t)cc * N2 + rowbase + w * 32 + rt * 16 + g * 4 + r] = v;
        }
    }
}

// ---- K3: per-row loss over 32 blocks; last block finishes the mean ----
__global__ __launch_bounds__(256) void k_loss(const float* __restrict__ partial,
                                              const float* __restrict__ diag,
                                              const float* __restrict__ posv,
                                              float* __restrict__ blocksum,
                                              unsigned int* __restrict__ counter,
                                              float* __restrict__ out) {
    int row = blockIdx.x * 256 + threadIdx.x;
    float sum = 0.0f;
    #pragma unroll
    for (int c = 0; c < 8; ++c) sum += partial[(size_t)c * N2 + row];
    sum -= __builtin_amdgcn_exp2f(diag[row]);           // remove diagonal term
    float lr = __builtin_amdgcn_logf(sum) * LN2 - posv[row & (BROWS - 1)];
    lr = wave_reduce(lr);
    __shared__ float red[4];
    if ((threadIdx.x & 63) == 0) red[threadIdx.x >> 6] = lr;
    __syncthreads();
    if (threadIdx.x == 0) {
        blocksum[blockIdx.x] = red[0] + red[1] + red[2] + red[3];
        __threadfence();                                  // publish blocksum
        unsigned int old = atomicAdd(counter, 1u);        // device-scope
        if (old == 31u) {                                 // last block finishes
            __threadfence();                              // acquire
            volatile const float* bs = blocksum;
            float t = 0.0f;
            for (int i = 0; i < 32; ++i) t += bs[i];
            out[0] = t * (1.0f / N2);
        }
    }
}

extern "C" void kernel_launch(void* const* d_in, const int* in_sizes, int n_in,
                              void* d_out, int out_size, void* d_ws, size_t ws_size,
                              hipStream_t stream) {
    const float* zi = (const float*)d_in[0];
    const float* zj = (const float*)d_in[1];
    float* out = (float*)d_out;

    char* ws = (char*)d_ws;
    unsigned short* zn    = (unsigned short*)ws;                       // 4 MB
    float* diag           = (float*)(ws + (4u << 20));                 // 32 KB
    float* posv           = (float*)(ws + (4u << 20) + (32u << 10));   // 16 KB
    float* blocksum       = (float*)(ws + (4u << 20) + (48u << 10));   // 128 B
    unsigned int* counter = (unsigned int*)(ws + (4u << 20) + (52u << 10));
    float* partial        = (float*)(ws + (4u << 20) + (64u << 10));   // 256 KB (8 slots)

    k_norm_pos<<<BROWS / 4, 256, 0, stream>>>(zi, zj, zn, diag, posv, counter);
    k_simsum<<<512, 256, 0, stream>>>(zn, partial);
    k_loss<<<32, 256, 0, stream>>>(partial, diag, posv, blocksum, counter, out);
}